// Round 4
// baseline (1878.031 us; speedup 1.0000x reference)
//
#include <hip/hip_runtime.h>
#include <cstdint>
#include <cstddef>

#define B_TOT 2048
#define T_TOT 50
#define NIN   620
#define NH    620
#define NCLS  11

// OpenBLAS sgemm K-panel size (SGEMM_DEFAULT_Q for Haswell/Zen targets).
// Per-element arithmetic: C = fl( fl(chain k<KC) + fl(chain k>=KC) ),
// each chain a single-accumulator ascending-k FMA sequence.
#define KC 384

// GEMM tiling: 128x64 block tile, 8x4 microtile, dual accumulators (panel split)
#define BM 128
#define BN 64
#define KB 16   // KC=384 is a multiple of KB -> split is tile-aligned

// ---------------------------------------------------------------------------
// Phase A: Z[m, n] = relu( X[r(m), :] . W1[n, :] )  fp32, OpenBLAS panel order.
// X rows for this t-chunk: m = b*ct + dt  ->  global row b*T_TOT + t0 + dt.
// ---------------------------------------------------------------------------
__global__ __launch_bounds__(256)
void gemm_relu_kernel(const float* __restrict__ X,
                      const float* __restrict__ W1,
                      float* __restrict__ Z,
                      int t0, int ct)
{
    __shared__ float As[KB][BM + 4];
    __shared__ float Bs[KB][BN + 4];

    const int tid = threadIdx.x;
    const int n0 = blockIdx.x * BN;
    const int m0 = blockIdx.y * BM;
    const int tx = tid & 15;   // n direction: 4 cols each
    const int ty = tid >> 4;   // m direction: 8 rows each

    // A staging: 128 rows x 4 k-quads = 512 tasks, 2 per thread
    size_t a_off[2];
    int    a_kl[2], a_row[2];
#pragma unroll
    for (int it = 0; it < 2; ++it) {
        int task = tid + it * 256;
        int row  = task >> 2;
        int kl   = (task & 3) * 4;
        a_row[it] = row;
        a_kl[it]  = kl;
        int m  = m0 + row;
        int bb = m / ct;
        int dt = m - bb * ct;
        a_off[it] = ((size_t)bb * T_TOT + (size_t)(t0 + dt)) * (size_t)NIN + kl;
    }
    // B staging: 64 rows x 4 k-quads = 256 tasks, 1 per thread
    const int b_row = tid >> 2;
    const int b_kl  = (tid & 3) * 4;
    const int b_n   = n0 + b_row;
    const int b_ok  = (b_n < NH);
    const size_t b_off = (size_t)b_n * NIN + b_kl;

    float acc1[8][4], acc2[8][4];   // panel k<KC / k>=KC
#pragma unroll
    for (int i = 0; i < 8; ++i)
#pragma unroll
        for (int j = 0; j < 4; ++j) { acc1[i][j] = 0.0f; acc2[i][j] = 0.0f; }

    for (int k0 = 0; k0 < NIN; k0 += KB) {
        // stage tiles (k-major in LDS); tail zero-fill adds fma(a,0,c)=c, exact
#pragma unroll
        for (int it = 0; it < 2; ++it) {
            int k = k0 + a_kl[it];
            float4 av = make_float4(0.f, 0.f, 0.f, 0.f);
            if (k < NIN) av = *(const float4*)(X + a_off[it] + k0);
            As[a_kl[it] + 0][a_row[it]] = av.x;
            As[a_kl[it] + 1][a_row[it]] = av.y;
            As[a_kl[it] + 2][a_row[it]] = av.z;
            As[a_kl[it] + 3][a_row[it]] = av.w;
        }
        {
            int k = k0 + b_kl;
            float4 bv = make_float4(0.f, 0.f, 0.f, 0.f);
            if (b_ok && k < NIN) bv = *(const float4*)(W1 + b_off + k0);
            Bs[b_kl + 0][b_row] = bv.x;
            Bs[b_kl + 1][b_row] = bv.y;
            Bs[b_kl + 2][b_row] = bv.z;
            Bs[b_kl + 3][b_row] = bv.w;
        }
        __syncthreads();

        if (k0 < KC) {
#pragma unroll
            for (int kk = 0; kk < KB; ++kk) {   // ascending k, panel 1
                float a[8], b[4];
#pragma unroll
                for (int i = 0; i < 8; ++i) a[i] = As[kk][ty * 8 + i];
#pragma unroll
                for (int j = 0; j < 4; ++j) b[j] = Bs[kk][tx * 4 + j];
#pragma unroll
                for (int i = 0; i < 8; ++i)
#pragma unroll
                    for (int j = 0; j < 4; ++j)
                        acc1[i][j] = fmaf(a[i], b[j], acc1[i][j]);
            }
        } else {
#pragma unroll
            for (int kk = 0; kk < KB; ++kk) {   // ascending k, panel 2
                float a[8], b[4];
#pragma unroll
                for (int i = 0; i < 8; ++i) a[i] = As[kk][ty * 8 + i];
#pragma unroll
                for (int j = 0; j < 4; ++j) b[j] = Bs[kk][tx * 4 + j];
#pragma unroll
                for (int i = 0; i < 8; ++i)
#pragma unroll
                    for (int j = 0; j < 4; ++j)
                        acc2[i][j] = fmaf(a[i], b[j], acc2[i][j]);
            }
        }
        __syncthreads();
    }

    // epilogue: merge panels (one rounded add), relu, store
#pragma unroll
    for (int i = 0; i < 8; ++i) {
        int m = m0 + ty * 8 + i;
        float* zr = Z + (size_t)m * NH;
        int n = n0 + tx * 4;
        if (n < NH) {           // n % 4 == 0, NH % 4 == 0 -> quad fully in/out
            float4 v;
            v.x = fmaxf(__fadd_rn(acc1[i][0], acc2[i][0]), 0.0f);
            v.y = fmaxf(__fadd_rn(acc1[i][1], acc2[i][1]), 0.0f);
            v.z = fmaxf(__fadd_rn(acc1[i][2], acc2[i][2]), 0.0f);
            v.w = fmaxf(__fadd_rn(acc1[i][3], acc2[i][3]), 0.0f);
            *(float4*)(zr + n) = v;
        }
    }
}

// ---------------------------------------------------------------------------
// Phase B: recurrence, fp32, np-bitwise. One wave per b; spikes staged in LDS;
// layer-2 dot = one lane per class, ascending-k fmaf chains split at KC.
// __fmul_rn/__fadd_rn block ffp-contract=fast from fusing membrane updates.
// ---------------------------------------------------------------------------
#define NWAVE 4
__global__ __launch_bounds__(256)
void snn_kernel(const float* __restrict__ Z,
                const float* __restrict__ W2,
                float* __restrict__ state,
                float* __restrict__ out,
                int t0, int ct)
{
    __shared__ float W2s[NCLS][NH];     // 27.3 KB
    __shared__ float Ss[NWAVE][NH];     // 9.9 KB

    const int tid = threadIdx.x;
    for (int i = tid; i < NCLS * NH; i += 256)
        ((float*)W2s)[i] = W2[i];
    __syncthreads();

    const int lane = tid & 63;
    const int wv   = tid >> 6;
    const int b    = blockIdx.x * NWAVE + wv;

    float* st_h1m = state;
    float* st_h1s = state + (size_t)B_TOT * NH;
    float* st_h2m = state + (size_t)2 * B_TOT * NH;
    float* st_h2s = st_h2m + (size_t)B_TOT * NCLS;
    float* st_acc = st_h2s + (size_t)B_TOT * NCLS;

    float h1m[10], h1s[10];
    float h2m = 0.f, h2s = 0.f, acc = 0.f;   // lane<11 owns class c=lane

    if (t0 == 0) {
#pragma unroll
        for (int i = 0; i < 10; ++i) { h1m[i] = 0.f; h1s[i] = 0.f; }
    } else {
#pragma unroll
        for (int i = 0; i < 10; ++i) {
            int k = i * 64 + lane;
            if (k < NH) {
                h1m[i] = st_h1m[(size_t)b * NH + k];
                h1s[i] = st_h1s[(size_t)b * NH + k];
            } else { h1m[i] = 0.f; h1s[i] = 0.f; }
        }
        if (lane < NCLS) {
            h2m = st_h2m[(size_t)b * NCLS + lane];
            h2s = st_h2s[(size_t)b * NCLS + lane];
            acc = st_acc[(size_t)b * NCLS + lane];
        }
    }

    for (int dt = 0; dt < ct; ++dt) {
        const float* z = Z + ((size_t)b * ct + dt) * NH;

        // layer-1 membrane update (np op order, each op separately rounded)
#pragma unroll
        for (int i = 0; i < 10; ++i) {
            int k = i * 64 + lane;
            if (k < NH) {
                float dec = __fmul_rn(__fmul_rn(h1m[i], 0.2f), (1.0f - h1s[i]));
                float m = __fadd_rn(dec, z[k]);
                float s = (m > 0.5f) ? 1.0f : 0.0f;
                h1m[i] = m; h1s[i] = s;
                Ss[wv][k] = s;
            }
        }
        __syncthreads();

        // layer-2: two ascending-k chains split at KC, merged by one add
        if (lane < NCLS) {
            const float4* w4 = (const float4*)&W2s[lane][0];
            const float4* s4 = (const float4*)&Ss[wv][0];
            float csumA = 0.0f;
#pragma unroll 4
            for (int q = 0; q < KC / 4; ++q) {          // k = 0..KC-1
                float4 w = w4[q];
                float4 s = s4[q];
                csumA = fmaf(s.x, w.x, csumA);
                csumA = fmaf(s.y, w.y, csumA);
                csumA = fmaf(s.z, w.z, csumA);
                csumA = fmaf(s.w, w.w, csumA);
            }
            float csumB = 0.0f;
#pragma unroll 4
            for (int q = KC / 4; q < NH / 4; ++q) {     // k = KC..NH-1
                float4 w = w4[q];
                float4 s = s4[q];
                csumB = fmaf(s.x, w.x, csumB);
                csumB = fmaf(s.y, w.y, csumB);
                csumB = fmaf(s.z, w.z, csumB);
                csumB = fmaf(s.w, w.w, csumB);
            }
            float csum = __fadd_rn(csumA, csumB);
            float dec = __fmul_rn(__fmul_rn(h2m, 0.2f), (1.0f - h2s));
            float m = __fadd_rn(dec, fmaxf(csum, 0.0f));
            float s = (m > 0.5f) ? 1.0f : 0.0f;
            h2m = m; h2s = s;
            acc = __fadd_rn(acc, s);   // small-int adds, exact
        }
        __syncthreads();   // protect Ss against next-iteration overwrite
    }

    if (t0 + ct >= T_TOT) {
        if (lane < NCLS)
            out[(size_t)b * NCLS + lane] = __fdiv_rn(acc, 50.0f);
    } else {
#pragma unroll
        for (int i = 0; i < 10; ++i) {
            int k = i * 64 + lane;
            if (k < NH) {
                st_h1m[(size_t)b * NH + k] = h1m[i];
                st_h1s[(size_t)b * NH + k] = h1s[i];
            }
        }
        if (lane < NCLS) {
            st_h2m[(size_t)b * NCLS + lane] = h2m;
            st_h2s[(size_t)b * NCLS + lane] = h2s;
            st_acc[(size_t)b * NCLS + lane] = acc;
        }
    }
}

// ---------------------------------------------------------------------------
extern "C" void kernel_launch(void* const* d_in, const int* in_sizes, int n_in,
                              void* d_out, int out_size, void* d_ws, size_t ws_size,
                              hipStream_t stream)
{
    const float* X  = (const float*)d_in[0];   // (2048, 50, 620) fp32
    const float* W1 = (const float*)d_in[1];   // (620, 620)
    const float* W2 = (const float*)d_in[2];   // (11, 620)
    float* out = (float*)d_out;                // (2048, 11) fp32

    const size_t state_floats = (size_t)2 * B_TOT * NH + (size_t)3 * B_TOT * NCLS;
    const size_t state_bytes  = state_floats * sizeof(float);
    const size_t bytes_per_t  = (size_t)B_TOT * NH * sizeof(float);

    size_t avail = (ws_size > state_bytes) ? (ws_size - state_bytes) : 0;
    int chunkT = (int)(avail / bytes_per_t);
    if (chunkT > T_TOT) chunkT = T_TOT;
    if (chunkT < 1) chunkT = 1;   // requires ws_size >= ~15.6 MB

    float* state = (float*)d_ws;
    float* Zbuf  = state + state_floats;

    for (int t0 = 0; t0 < T_TOT; t0 += chunkT) {
        int ct = (T_TOT - t0 < chunkT) ? (T_TOT - t0) : chunkT;
        dim3 ggrid((NH + BN - 1) / BN, (B_TOT * ct) / BM);
        gemm_relu_kernel<<<ggrid, 256, 0, stream>>>(X, W1, Zbuf, t0, ct);
        snn_kernel<<<dim3(B_TOT / NWAVE), 256, 0, stream>>>(Zbuf, W2, state, out, t0, ct);
    }
}

// Round 5
// 1557.408 us; speedup vs baseline: 1.2059x; 1.2059x over previous
//
#include <hip/hip_runtime.h>
#include <cstdint>
#include <cstddef>

#define B_TOT 2048
#define T_TOT 50
#define NIN   620
#define NH    620
#define NCLS  11

// OpenBLAS sgemm K-panel size (SGEMM_DEFAULT_Q). Per-element arithmetic:
// C = fl( fl(chain k<KC) + fl(chain k>=KC) ), each chain single-accumulator
// ascending-k fmaf. THIS RECIPE IS BITWISE-VERIFIED (R4, absmax=0) — do not
// change summation order, only scheduling.
#define KC 384

// GEMM tiling: 128x128 block tile, 8x8 microtile, KB=32.
// Panel split handled by dumping chain-A accs raw to Z at k0==KC-KB, then
// reusing the same 64 acc regs for chain B; epilogue merges with one
// __fadd_rn (bitwise same as dual-acc R4 version).
#define BM 128
#define BN 128
#define KB 32   // KC % KB == 0 -> split is tile-aligned

__global__ __launch_bounds__(256, 3)
void gemm_relu_kernel(const float* __restrict__ X,
                      const float* __restrict__ W1,
                      float* __restrict__ Z,
                      int t0, int ct)
{
    __shared__ float As[KB][BM + 4];
    __shared__ float Bs[KB][BN + 4];

    const int tid = threadIdx.x;
    const int n0 = blockIdx.x * BN;
    const int m0 = blockIdx.y * BM;
    const int tx = tid & 15;   // n direction, 8 cols each
    const int ty = tid >> 4;   // m direction, 8 rows each

    // Staging: tile = 128 rows x 8 k-quads = 1024 float4 tasks, 4 per thread.
    // Lanes 0..7 cover one row's 32 k's -> 128B contiguous per 8 lanes.
    size_t a_off[4];
    size_t b_off[4];
    int    s_row[4], s_kl[4], b_ok[4];
#pragma unroll
    for (int it = 0; it < 4; ++it) {
        int task = tid + it * 256;
        int row  = task >> 3;          // 0..127
        int kl   = (task & 7) * 4;     // 0..28
        s_row[it] = row;
        s_kl[it]  = kl;
        int m  = m0 + row;
        int bb = m / ct;
        int dt = m - bb * ct;
        a_off[it] = ((size_t)bb * T_TOT + (size_t)(t0 + dt)) * (size_t)NIN + kl;
        int n = n0 + row;
        b_off[it] = (size_t)n * NIN + kl;
        b_ok[it]  = (n < NH);
    }

    float acc[8][8];
#pragma unroll
    for (int i = 0; i < 8; ++i)
#pragma unroll
        for (int j = 0; j < 8; ++j) acc[i][j] = 0.0f;

    float* zr0 = Z + (size_t)(m0 + ty * 8) * NH + (n0 + tx * 8);

    for (int k0 = 0; k0 < NIN; k0 += KB) {
        // ---- stage (k-major transposed; zero-fill tail: fma(0,0,c)=c exact)
#pragma unroll
        for (int it = 0; it < 4; ++it) {
            int k = k0 + s_kl[it];
            float4 av = make_float4(0.f, 0.f, 0.f, 0.f);
            if (k < NIN) av = *(const float4*)(X + a_off[it] + k0);
            As[s_kl[it] + 0][s_row[it]] = av.x;
            As[s_kl[it] + 1][s_row[it]] = av.y;
            As[s_kl[it] + 2][s_row[it]] = av.z;
            As[s_kl[it] + 3][s_row[it]] = av.w;
            float4 bv = make_float4(0.f, 0.f, 0.f, 0.f);
            if (b_ok[it] && k < NIN) bv = *(const float4*)(W1 + b_off[it] + k0);
            Bs[s_kl[it] + 0][s_row[it]] = bv.x;
            Bs[s_kl[it] + 1][s_row[it]] = bv.y;
            Bs[s_kl[it] + 2][s_row[it]] = bv.z;
            Bs[s_kl[it] + 3][s_row[it]] = bv.w;
        }
        __syncthreads();

        // ---- compute: ascending k, 64 fma per kk
#pragma unroll 8
        for (int kk = 0; kk < KB; ++kk) {
            float a[8], b[8];
#pragma unroll
            for (int i = 0; i < 8; ++i) a[i] = As[kk][ty * 8 + i];
#pragma unroll
            for (int j = 0; j < 8; ++j) b[j] = Bs[kk][tx * 8 + j];
#pragma unroll
            for (int i = 0; i < 8; ++i)
#pragma unroll
                for (int j = 0; j < 8; ++j)
                    acc[i][j] = fmaf(a[i], b[j], acc[i][j]);
        }
        __syncthreads();

        // ---- panel boundary: dump chain-A raw to Z, zero accs (uniform branch)
        if (k0 + KB == KC) {
#pragma unroll
            for (int i = 0; i < 8; ++i) {
                float* zr = zr0 + (size_t)i * NH;
#pragma unroll
                for (int j = 0; j < 8; j += 4) {
                    int n = n0 + tx * 8 + j;
                    if (n < NH)
                        *(float4*)(zr + j) = make_float4(acc[i][j], acc[i][j + 1],
                                                         acc[i][j + 2], acc[i][j + 3]);
                }
            }
#pragma unroll
            for (int i = 0; i < 8; ++i)
#pragma unroll
                for (int j = 0; j < 8; ++j) acc[i][j] = 0.0f;
            // stores drain at the next iteration's __syncthreads (vmcnt(0));
            // same-thread readback in epilogue is L2-coherent.
        }
    }

    // ---- epilogue: merge panels (one rounded add), relu, store
#pragma unroll
    for (int i = 0; i < 8; ++i) {
        float* zr = zr0 + (size_t)i * NH;
#pragma unroll
        for (int j = 0; j < 8; j += 4) {
            int n = n0 + tx * 8 + j;
            if (n < NH) {
                float4 p = *(const float4*)(zr + j);   // chain A
                float4 v;
                v.x = fmaxf(__fadd_rn(p.x, acc[i][j + 0]), 0.0f);
                v.y = fmaxf(__fadd_rn(p.y, acc[i][j + 1]), 0.0f);
                v.z = fmaxf(__fadd_rn(p.z, acc[i][j + 2]), 0.0f);
                v.w = fmaxf(__fadd_rn(p.w, acc[i][j + 3]), 0.0f);
                *(float4*)(zr + j) = v;
            }
        }
    }
}

// ---------------------------------------------------------------------------
// Phase B: recurrence, fp32, np-bitwise. One wave per b; spikes in LDS;
// layer-2 = two ascending-k chains split at KC, run CONCURRENTLY on lanes
// c (panel A) and c+32 (panel B), merged via shuffle + one __fadd_rn.
// ---------------------------------------------------------------------------
#define NWAVE 4
__global__ __launch_bounds__(256)
void snn_kernel(const float* __restrict__ Z,
                const float* __restrict__ W2,
                float* __restrict__ state,
                float* __restrict__ out,
                int t0, int ct)
{
    __shared__ float W2s[NCLS][NH];     // 27.3 KB
    __shared__ float Ss[NWAVE][NH];     // 9.9 KB

    const int tid = threadIdx.x;
    for (int i = tid; i < NCLS * NH; i += 256)
        ((float*)W2s)[i] = W2[i];
    __syncthreads();

    const int lane = tid & 63;
    const int wv   = tid >> 6;
    const int b    = blockIdx.x * NWAVE + wv;

    float* st_h1m = state;
    float* st_h1s = state + (size_t)B_TOT * NH;
    float* st_h2m = state + (size_t)2 * B_TOT * NH;
    float* st_h2s = st_h2m + (size_t)B_TOT * NCLS;
    float* st_acc = st_h2s + (size_t)B_TOT * NCLS;

    float h1m[10], h1s[10];
    float h2m = 0.f, h2s = 0.f, acc = 0.f;   // lane<11 owns class c=lane

    if (t0 == 0) {
#pragma unroll
        for (int i = 0; i < 10; ++i) { h1m[i] = 0.f; h1s[i] = 0.f; }
    } else {
#pragma unroll
        for (int i = 0; i < 10; ++i) {
            int k = i * 64 + lane;
            if (k < NH) {
                h1m[i] = st_h1m[(size_t)b * NH + k];
                h1s[i] = st_h1s[(size_t)b * NH + k];
            } else { h1m[i] = 0.f; h1s[i] = 0.f; }
        }
        if (lane < NCLS) {
            h2m = st_h2m[(size_t)b * NCLS + lane];
            h2s = st_h2s[(size_t)b * NCLS + lane];
            acc = st_acc[(size_t)b * NCLS + lane];
        }
    }

    const int cls   = lane & 31;
    const int qbase = (lane < 32) ? 0 : (KC / 4);                 // 0 / 96
    const int qcnt  = (lane < 32) ? (KC / 4) : ((NH - KC) / 4);   // 96 / 59

    for (int dt = 0; dt < ct; ++dt) {
        const float* z = Z + ((size_t)b * ct + dt) * NH;

        // layer-1 membrane (np op order, each op separately rounded)
#pragma unroll
        for (int i = 0; i < 10; ++i) {
            int k = i * 64 + lane;
            if (k < NH) {
                float dec = __fmul_rn(__fmul_rn(h1m[i], 0.2f), (1.0f - h1s[i]));
                float m = __fadd_rn(dec, z[k]);
                float s = (m > 0.5f) ? 1.0f : 0.0f;
                h1m[i] = m; h1s[i] = s;
                Ss[wv][k] = s;
            }
        }
        __syncthreads();

        // layer-2: both panel chains in parallel (lane c: A, lane c+32: B)
        float csum = 0.0f;
        if (cls < NCLS) {
            const float4* w4 = (const float4*)&W2s[cls][0] + qbase;
            const float4* s4 = (const float4*)&Ss[wv][0] + qbase;
            for (int q = 0; q < qcnt; ++q) {      // ascending k within panel
                float4 w = w4[q];
                float4 s = s4[q];
                csum = fmaf(s.x, w.x, csum);
                csum = fmaf(s.y, w.y, csum);
                csum = fmaf(s.z, w.z, csum);
                csum = fmaf(s.w, w.w, csum);
            }
        }
        float csumB = __shfl_xor(csum, 32, 64);   // lane c receives panel B
        if (lane < NCLS) {
            float ctot = __fadd_rn(csum, csumB);  // single panel-merge add
            float dec = __fmul_rn(__fmul_rn(h2m, 0.2f), (1.0f - h2s));
            float m = __fadd_rn(dec, fmaxf(ctot, 0.0f));
            float s = (m > 0.5f) ? 1.0f : 0.0f;
            h2m = m; h2s = s;
            acc = __fadd_rn(acc, s);              // small-int adds, exact
        }
        __syncthreads();   // protect Ss against next-iteration overwrite
    }

    if (t0 + ct >= T_TOT) {
        if (lane < NCLS)
            out[(size_t)b * NCLS + lane] = __fdiv_rn(acc, 50.0f);
    } else {
#pragma unroll
        for (int i = 0; i < 10; ++i) {
            int k = i * 64 + lane;
            if (k < NH) {
                st_h1m[(size_t)b * NH + k] = h1m[i];
                st_h1s[(size_t)b * NH + k] = h1s[i];
            }
        }
        if (lane < NCLS) {
            st_h2m[(size_t)b * NCLS + lane] = h2m;
            st_h2s[(size_t)b * NCLS + lane] = h2s;
            st_acc[(size_t)b * NCLS + lane] = acc;
        }
    }
}

// ---------------------------------------------------------------------------
extern "C" void kernel_launch(void* const* d_in, const int* in_sizes, int n_in,
                              void* d_out, int out_size, void* d_ws, size_t ws_size,
                              hipStream_t stream)
{
    const float* X  = (const float*)d_in[0];   // (2048, 50, 620) fp32
    const float* W1 = (const float*)d_in[1];   // (620, 620)
    const float* W2 = (const float*)d_in[2];   // (11, 620)
    float* out = (float*)d_out;                // (2048, 11) fp32

    const size_t state_floats = (size_t)2 * B_TOT * NH + (size_t)3 * B_TOT * NCLS;
    const size_t state_bytes  = state_floats * sizeof(float);
    const size_t bytes_per_t  = (size_t)B_TOT * NH * sizeof(float);

    size_t avail = (ws_size > state_bytes) ? (ws_size - state_bytes) : 0;
    int chunkT = (int)(avail / bytes_per_t);
    if (chunkT > T_TOT) chunkT = T_TOT;
    if (chunkT < 1) chunkT = 1;   // requires ws_size >= ~15.6 MB

    float* state = (float*)d_ws;
    float* Zbuf  = state + state_floats;

    for (int t0 = 0; t0 < T_TOT; t0 += chunkT) {
        int ct = (T_TOT - t0 < chunkT) ? (T_TOT - t0) : chunkT;
        dim3 ggrid((NH + BN - 1) / BN, (B_TOT * ct) / BM);
        gemm_relu_kernel<<<ggrid, 256, 0, stream>>>(X, W1, Zbuf, t0, ct);
        snn_kernel<<<dim3(B_TOT / NWAVE), 256, 0, stream>>>(Zbuf, W2, state, out, t0, ct);
    }
}